// Round 1
// 665.150 us; speedup vs baseline: 1.0161x; 1.0161x over previous
//
#include <hip/hip_runtime.h>
#include <math.h>

// FourierBlock: q:(B,N,L,H,E) f32 -> out:(B,N,H,E,L) f32
// Only bins INDEX=(1,4,5) of the rfft are consumed; outputs land in bins 0..2.
// So: 3-bin DFT -> per-(n,h) complex channel mix -> closed-form 3-bin irfft.
static constexpr int kB = 8;
static constexpr int kN = 2000;
static constexpr int kL = 64;
static constexpr int kH = 4;
static constexpr int kE = 16;
static constexpr int kC = kH * kE;   // 64 channels
static constexpr int kM = 3;         // modes

__global__ __launch_bounds__(256) void fourier_block_kernel(
    const float* __restrict__ q,
    const float* __restrict__ w1,
    const float* __restrict__ w2,
    float* __restrict__ out)
{
    __shared__ float xs[kL * kC];          // 16 KB, [t][c]
    __shared__ float cosT[kL], sinT[kL];   // twiddles: angle 2*pi*j/64
    __shared__ float xgRe[kC * kM], xgIm[kC * kM];  // [c][m]
    __shared__ float MRe[kC * kM],  MIm[kC * kM];   // [(h*16+o)][m]

    const int tid = threadIdx.x;
    const int blk = blockIdx.x;          // = n*kB + b
    const int n = blk >> 3;
    const int b = blk & 7;

    // ---- twiddle tables (exact sinf/cosf, 64 lanes) ----
    if (tid < kL) {
        float ang = (float)tid * (2.0f * (float)M_PI / (float)kL);
        cosT[tid] = cosf(ang);
        sinT[tid] = sinf(ang);
    }

    // ---- stage q slice (b,n): 4096 contiguous floats, [t][h*E+i] ----
    {
        const float4* __restrict__ src =
            (const float4*)(q + (size_t)(b * kN + n) * (kL * kC));
        float4* dst = (float4*)xs;
        #pragma unroll
        for (int k = 0; k < 4; ++k)
            dst[tid + k * 256] = src[tid + k * 256];
    }
    __syncthreads();

    // ---- 3-bin forward DFT: xg[c][m] = sum_t x[t][c] * e^{-2pi i f_m t/64} ----
    if (tid < kC * kM) {                 // 192 threads
        const int c = tid & 63;          // wave-uniform m per wave
        const int m = tid >> 6;
        const int f = (m == 0) ? 1 : (m == 1) ? 4 : 5;
        float accR = 0.0f, accI = 0.0f;
        int j = 0;
        #pragma unroll 8
        for (int t = 0; t < kL; ++t) {
            float x = xs[t * kC + c];
            accR = fmaf(x, cosT[j], accR);
            accI = fmaf(-x, sinT[j], accI);
            j = (j + f) & 63;
        }
        xgRe[c * kM + m] = accR;
        xgIm[c * kM + m] = accI;
    }
    __syncthreads();

    // ---- complex channel mix: M[h][o][m] = sum_i xg[h*16+i][m] * (w1 + i w2) ----
    if (tid < kC * kM) {                 // 192 threads: (h, o, m)
        const int h = tid / 48;
        const int r = tid % 48;
        const int o = r / 3;
        const int m = r % 3;
        const size_t wbase = (size_t)(n * kH + h) * (kE * kE * kM) + o * kM + m;
        const float* __restrict__ p1 = w1 + wbase;
        const float* __restrict__ p2 = w2 + wbase;
        float accR = 0.0f, accI = 0.0f;
        #pragma unroll
        for (int i = 0; i < kE; ++i) {
            float wr = p1[i * (kE * kM)];
            float wi = p2[i * (kE * kM)];
            float xr = xgRe[(h * kE + i) * kM + m];
            float xi = xgIm[(h * kE + i) * kM + m];
            accR = fmaf(xr, wr, fmaf(-xi, wi, accR));
            accI = fmaf(xr, wi, fmaf(xi, wr, accI));
        }
        MRe[(h * kE + o) * kM + m] = accR;
        MIm[(h * kE + o) * kM + m] = accI;
    }
    __syncthreads();

    // ---- analytic irfft, bins 0..2 only; irfft ignores Im(bin0) ----
    // out[t] = (1/64)*( M0r + 2*(M1r cos(th) - M1i sin(th)) + 2*(M2r cos(2th) - M2i sin(2th)) )
    //
    // Store mapping chosen for FULL per-instruction coalescing: store k has
    // lane tid writing float4 index (k*256 + tid) of this block's 4096-float
    // output slab -> each wave instruction writes 1 KB contiguous (full 128B
    // lines, no partial-line RMW). Decode: c = k*16 + tid/16, t = 4*(tid&15)+u.
    {
        const int t0 = (tid & 15) * 4;   // 4 consecutive t per thread (same for all k)
        const float inv = 1.0f / 64.0f;
        float c1[4], s1[4], c2[4], s2[4];
        #pragma unroll
        for (int u = 0; u < 4; ++u) {
            int t  = t0 + u;
            int t2 = (2 * t) & 63;
            c1[u] = cosT[t];  s1[u] = sinT[t];
            c2[u] = cosT[t2]; s2[u] = sinT[t2];
        }
        float4* __restrict__ obase4 =
            (float4*)(out + (size_t)(b * kN + n) * (kC * kL));
        #pragma unroll
        for (int k = 0; k < 4; ++k) {
            const int c = k * 16 + (tid >> 4);       // output channel h*16+o
            const float m0r = MRe[c * kM + 0];
            const float m1r = 2.0f * MRe[c * kM + 1], m1i = 2.0f * MIm[c * kM + 1];
            const float m2r = 2.0f * MRe[c * kM + 2], m2i = 2.0f * MIm[c * kM + 2];
            float4 vv;
            #pragma unroll
            for (int u = 0; u < 4; ++u) {
                float v = m0r;
                v = fmaf(m1r,  c1[u], v);
                v = fmaf(-m1i, s1[u], v);
                v = fmaf(m2r,  c2[u], v);
                v = fmaf(-m2i, s2[u], v);
                ((float*)&vv)[u] = v * inv;
            }
            obase4[k * 256 + tid] = vv;
        }
    }
}

extern "C" void kernel_launch(void* const* d_in, const int* in_sizes, int n_in,
                              void* d_out, int out_size, void* d_ws, size_t ws_size,
                              hipStream_t stream) {
    // setup_inputs order: q, k, v, mask, weights1, weights2
    const float* q  = (const float*)d_in[0];
    const float* w1 = (const float*)d_in[4];
    const float* w2 = (const float*)d_in[5];
    float* out = (float*)d_out;
    fourier_block_kernel<<<dim3(kB * kN), dim3(256), 0, stream>>>(q, w1, w2, out);
}